// Round 7
// baseline (225.239 us; speedup 1.0000x reference)
//
#include <hip/hip_runtime.h>
#include <hip/hip_bf16.h>
#include <math.h>
#include <stdint.h>

// ---------- types ----------
typedef __attribute__((ext_vector_type(8))) short short8;     // 8 x bf16 (MFMA A/B frag)
typedef __attribute__((ext_vector_type(4))) float floatx4;    // MFMA C/D frag
typedef __attribute__((ext_vector_type(4))) unsigned short ushort4v;

// ---------- helpers ----------
__device__ __forceinline__ void gload_lds16(const void* g, void* lds) {
    __builtin_amdgcn_global_load_lds(
        (__attribute__((address_space(1))) void*)(g),
        (__attribute__((address_space(3))) void*)(lds), 16, 0, 0);
}
__device__ __forceinline__ float bf16bits_to_f(unsigned short u) {
    union { unsigned int i; float f; } x; x.i = ((unsigned int)u) << 16; return x.f;
}
__device__ __forceinline__ unsigned short f_to_bf16bits(float f) {
    union { float f; unsigned int i; } x; x.f = f;
    unsigned int lsb = (x.i >> 16) & 1u;
    x.i += 0x7fffu + lsb;                      // round-to-nearest-even
    return (unsigned short)(x.i >> 16);
}
// raw barriers with hand-rolled waitcnt (gfx9 encoding:
// [3:0]=vmcnt lo, [6:4]=expcnt, [11:8]=lgkmcnt, [15:14]=vmcnt hi)
__device__ __forceinline__ void barrier_vm0() {
    __builtin_amdgcn_s_waitcnt(0x0F70);  // vmcnt(0) only
    __builtin_amdgcn_s_barrier();
}
__device__ __forceinline__ void barrier_lgkm0() {
    __builtin_amdgcn_s_waitcnt(0xC07F);  // lgkmcnt(0) only — K prefetch stays in flight
    __builtin_amdgcn_s_barrier();
}

// =====================================================================
// One-dispatch fp32->bf16 conversion: Q,K,V (12288 blocks) + W x3 (768) +
// b x3 (3). grid 13059.
// =====================================================================
__global__ __launch_bounds__(256) void conv_all_kernel(
    const float* __restrict__ Q, const float* __restrict__ K, const float* __restrict__ V,
    const float* __restrict__ Wq, const float* __restrict__ Wk, const float* __restrict__ Wv,
    const float* __restrict__ bq, const float* __restrict__ bk, const float* __restrict__ bv,
    unsigned short* __restrict__ qkv,  // 3 slots stride 4194304
    unsigned short* __restrict__ Wo,   // 3 slots stride 262144
    unsigned short* __restrict__ bo)   // 3 slots stride 512
{
    const int gid = blockIdx.x;
    const float* src; unsigned short* dst; int idx;
    if (gid < 12288) {
        const int seg = gid >> 12, blk = gid & 4095;
        src = (seg == 0) ? Q : (seg == 1) ? K : V;
        dst = qkv + (size_t)seg * 4194304;
        idx = (blk * 256 + threadIdx.x) * 4;
    } else if (gid < 13056) {
        const int t = gid - 12288, m = t >> 8, blk = t & 255;
        src = (m == 0) ? Wq : (m == 1) ? Wk : Wv;
        dst = Wo + (size_t)m * 262144;
        idx = (blk * 256 + threadIdx.x) * 4;
    } else {
        const int m = gid - 13056;
        if (threadIdx.x >= 128) return;
        src = (m == 0) ? bq : (m == 1) ? bk : bv;
        dst = bo + (size_t)m * 512;
        idx = threadIdx.x * 4;
    }
    float4 v = *(const float4*)&src[idx];
    ushort4v o;
    o[0] = f_to_bf16bits(v.x); o[1] = f_to_bf16bits(v.y);
    o[2] = f_to_bf16bits(v.z); o[3] = f_to_bf16bits(v.w);
    *(ushort4v*)&dst[idx] = o;
}

// single-input fp32 -> bf16 (small-ws fallback). grid 4096.
__global__ __launch_bounds__(256) void conv1_kernel(
    const float* __restrict__ in, unsigned short* __restrict__ out)
{
    const int idx = (blockIdx.x * 256 + threadIdx.x) * 4;
    float4 v = *(const float4*)&in[idx];
    ushort4v o;
    o[0] = f_to_bf16bits(v.x); o[1] = f_to_bf16bits(v.y);
    o[2] = f_to_bf16bits(v.z); o[3] = f_to_bf16bits(v.w);
    *(ushort4v*)&out[idx] = o;
}

// W/b conversion only (fallback path). grid (257,3).
__global__ __launch_bounds__(256) void conv_wb_kernel(
    const float* __restrict__ Wq, const float* __restrict__ Wk, const float* __restrict__ Wv,
    const float* __restrict__ bq, const float* __restrict__ bk, const float* __restrict__ bv,
    unsigned short* __restrict__ Wo, unsigned short* __restrict__ bo)
{
    const int m = blockIdx.y;
    const float* W = (m == 0) ? Wq : (m == 1) ? Wk : Wv;
    const float* b = (m == 0) ? bq : (m == 1) ? bk : bv;
    if (blockIdx.x < 256) {
        const int idx = (blockIdx.x * 256 + threadIdx.x) * 4;
        float4 v = *(const float4*)&W[idx];
        ushort4v o;
        o[0] = f_to_bf16bits(v.x); o[1] = f_to_bf16bits(v.y);
        o[2] = f_to_bf16bits(v.z); o[3] = f_to_bf16bits(v.w);
        *(ushort4v*)&Wo[(size_t)m * 262144 + idx] = o;
    } else if (threadIdx.x < 128) {
        const int idx = threadIdx.x * 4;
        float4 v = *(const float4*)&b[idx];
        ushort4v o;
        o[0] = f_to_bf16bits(v.x); o[1] = f_to_bf16bits(v.y);
        o[2] = f_to_bf16bits(v.z); o[3] = f_to_bf16bits(v.w);
        *(ushort4v*)&bo[(size_t)m * 512 + idx] = o;
    }
}

// =====================================================================
// Projection: C[m,n] = sum_k X[m,k]*W[n,k] + b[n]. M=8192,N=512,K=512.
// grid (256, nmodes); mode = mode_base + blockIdx.y.
// mode 0: q (scaled), 1: k, 2: v stored in PV-B-frag-native layout:
//   V6 elem(b,d,k) at  b*2097152 + (d>>4)*65536 + (k>>3)*128 + (d&15)*8 + (k&7)
// =====================================================================
__global__ __launch_bounds__(256, 2) void proj_kernel(
    const unsigned short* __restrict__ Xall,
    size_t xstride, int mode_base,
    const unsigned short* __restrict__ Wall,  // 3 slots stride 262144
    const unsigned short* __restrict__ ball,  // 3 slots stride 512
    unsigned short* __restrict__ qbuf,        // [8192,512] pre-scaled
    unsigned short* __restrict__ kbuf,        // [8192,512]
    unsigned short* __restrict__ vTbuf,       // V6 layout, 2*2097152 elems
    float qscale)
{
    __shared__ __align__(16) unsigned short Xs[128 * 64];
    __shared__ __align__(16) unsigned short Ws[128 * 64];

    const int mode = mode_base + blockIdx.y;
    const unsigned short* X = Xall + (size_t)blockIdx.y * xstride;
    const unsigned short* W = Wall + (size_t)mode * 262144;
    const unsigned short* bias = ball + (size_t)mode * 512;

    const int tid = threadIdx.x;
    const int wave = tid >> 6, lane = tid & 63, quad = lane >> 4, l15 = lane & 15;
    const int m0 = (int)(blockIdx.x >> 2) << 7;
    const int n0 = (int)(blockIdx.x & 3) << 7;
    const int mw = (wave >> 1) << 6, nw = (wave & 1) << 6;

    floatx4 acc[4][4];
    #pragma unroll
    for (int i = 0; i < 4; i++)
        #pragma unroll
        for (int j = 0; j < 4; j++) acc[i][j] = floatx4{0.f, 0.f, 0.f, 0.f};

    for (int kt = 0; kt < 512; kt += 64) {
        #pragma unroll
        for (int i = 0; i < 4; i++) {
            const int r0 = wave * 32 + i * 8;
            gload_lds16(X + (size_t)(m0 + r0 + (lane >> 3)) * 512 + kt + (lane & 7) * 8, &Xs[r0 * 64]);
            gload_lds16(W + (size_t)(n0 + r0 + (lane >> 3)) * 512 + kt + (lane & 7) * 8, &Ws[r0 * 64]);
        }
        __syncthreads();
        #pragma unroll
        for (int kk = 0; kk < 64; kk += 32) {
            short8 a[4], b[4];
            #pragma unroll
            for (int i = 0; i < 4; i++) a[i] = *(const short8*)&Xs[(mw + 16 * i + l15) * 64 + kk + quad * 8];
            #pragma unroll
            for (int j = 0; j < 4; j++) b[j] = *(const short8*)&Ws[(nw + 16 * j + l15) * 64 + kk + quad * 8];
            #pragma unroll
            for (int i = 0; i < 4; i++)
                #pragma unroll
                for (int j = 0; j < 4; j++)
                    acc[i][j] = __builtin_amdgcn_mfma_f32_16x16x32_bf16(a[i], b[j], acc[i][j], 0, 0, 0);
        }
        __syncthreads();
    }

    float bfj[4];
    #pragma unroll
    for (int j = 0; j < 4; j++) bfj[j] = bf16bits_to_f(bias[n0 + nw + 16 * j + l15]);

    if (mode < 2) {
        unsigned short* out = (mode == 0) ? qbuf : kbuf;
        const float s = (mode == 0) ? qscale : 1.0f;
        #pragma unroll
        for (int i = 0; i < 4; i++) {
            const int mrow = m0 + mw + 16 * i + quad * 4;   // C/D: row = quad*4+reg
            #pragma unroll
            for (int j = 0; j < 4; j++) {
                const int n = n0 + nw + 16 * j + l15;       // C/D: col = lane&15
                #pragma unroll
                for (int r = 0; r < 4; r++)
                    out[(size_t)(mrow + r) * 512 + n] = f_to_bf16bits((acc[i][j][r] + bfj[j]) * s);
            }
        }
    } else {
        // V6 layout: 4 consecutive keys -> 8B store
        #pragma unroll
        for (int i = 0; i < 4; i++) {
            const int mrow = m0 + mw + 16 * i + quad * 4;
            const int bb = mrow >> 12;
            const int k4 = mrow & 4095;
            const size_t kpart = (size_t)bb * 2097152 + (size_t)(k4 >> 3) * 128 + (k4 & 7);
            #pragma unroll
            for (int j = 0; j < 4; j++) {
                const int n = n0 + nw + 16 * j + l15;
                ushort4v pk;
                #pragma unroll
                for (int r = 0; r < 4; r++) pk[r] = f_to_bf16bits(acc[i][j][r] + bfj[j]);
                *(ushort4v*)&vTbuf[kpart + (size_t)(n >> 4) * 65536 + (n & 15) * 8] = pk;
            }
        }
    }
}

// =====================================================================
// Flash attention v4: double-buffered Ks + raw-barrier fine waitcnt.
// Per iter:  B1(vmcnt0+bar; K(it) was prefetched a full iter ago -> ~free)
//   -> issue V(it) reg loads, then K(it+1) DMA into other buffer
//   -> S-phase (Ks[buf]) -> exp/Ps -> B2(lgkmcnt0+bar; K prefetch in flight)
//   -> PV (compiler vmcnt leaves younger DMA outstanding).
// LDS = 2*33.3 + 5 = 71.6 KB -> 2 WG/CU (reg-capped there anyway).
// =====================================================================
template <int NSPLIT>
__global__ __launch_bounds__(256, 2) void attn_kernel(
    const unsigned short* __restrict__ q,    // [8192,512] pre-scaled
    const unsigned short* __restrict__ k,    // [8192,512]
    const unsigned short* __restrict__ vT,   // V6 layout
    unsigned short* __restrict__ num,        // [NSPLIT,8192,512] permuted bf16 partials
    float* __restrict__ denom)               // [NSPLIT,8192]
{
    constexpr int TK  = 32;
    constexpr int KST = 520;   // 512 + 8 pad
    constexpr int PST = 40;    // 32 + 8 pad
    __shared__ __align__(16) unsigned short Ks[2][TK * KST];  // 66.6 KB
    __shared__ __align__(16) unsigned short Ps[64 * PST];     // 5 KB

    const int tid = threadIdx.x;
    const int wave = tid >> 6, lane = tid & 63, quad = lane >> 4, l15 = lane & 15;
    const int bid = blockIdx.x;
    const int sp   = bid & (NSPLIT - 1);
    const int qblk = bid / NSPLIT;
    const int bb = qblk >> 6;              // batch
    const int q0 = (qblk & 63) << 6;       // q-tile start within batch
    const size_t rowbase = (size_t)bb * 4096 + q0;

    // Q fragments for this wave's 16 rows: A[m=lane&15][k=quad*8+j], 16 k-steps
    short8 qf[16];
    {
        const unsigned short* qrow = q + (rowbase + 16 * wave + l15) * 512;
        #pragma unroll
        for (int t = 0; t < 16; t++) qf[t] = *(const short8*)&qrow[t * 32 + quad * 8];
    }

    floatx4 oacc[4][8];                    // rows 16i+quad*4+r, cols 128*wave+16c+l15
    #pragma unroll
    for (int i = 0; i < 4; i++)
        #pragma unroll
        for (int c = 0; c < 8; c++) oacc[i][c] = floatx4{0.f, 0.f, 0.f, 0.f};
    float dsum[4] = {0.f, 0.f, 0.f, 0.f};

    const unsigned short* kb = k + (size_t)bb * 4096 * 512;
    const unsigned short* vbase = vT + (size_t)bb * 2097152
                                + (size_t)(8 * wave) * 65536 + quad * 128 + l15 * 8;

    const int jbeg = sp * (4096 / NSPLIT);
    constexpr int NITER = (4096 / NSPLIT) / TK;

    // preamble: stage first K tile into buffer 0
    #pragma unroll
    for (int r = 0; r < 8; r++) {
        const int row = wave * 8 + r;
        gload_lds16(kb + (size_t)(jbeg + row) * 512 + lane * 8, &Ks[0][row * KST]);
    }

    for (int it = 0; it < NITER; ++it) {
        const int j0 = jbeg + it * TK;
        const int buf = it & 1;

        barrier_vm0();   // B1: K(it) resident (prefetched an iter ago)

        // V fragments first (so PV's compiler vmcnt leaves K DMA in flight)
        short8 vf[8];
        #pragma unroll
        for (int c = 0; c < 8; c++)
            vf[c] = *(const short8*)&vbase[(size_t)c * 65536 + (j0 << 4)];

        // prefetch next K tile into the other buffer
        if (it + 1 < NITER) {
            #pragma unroll
            for (int r = 0; r < 8; r++) {
                const int row = wave * 8 + r;
                gload_lds16(kb + (size_t)(j0 + TK + row) * 512 + lane * 8,
                            &Ks[buf ^ 1][row * KST]);
            }
        }

        // --- S = q . K^T for this wave's 16 rows x 32 keys ---
        floatx4 sA[2], sB[2];
        sA[0] = sA[1] = sB[0] = sB[1] = floatx4{0.f, 0.f, 0.f, 0.f};
        #pragma unroll
        for (int t = 0; t < 16; t += 2) {
            #pragma unroll
            for (int c = 0; c < 2; c++) {
                short8 b0 = *(const short8*)&Ks[buf][(c * 16 + l15) * KST + t * 32 + quad * 8];
                sA[c] = __builtin_amdgcn_mfma_f32_16x16x32_bf16(qf[t], b0, sA[c], 0, 0, 0);
                short8 b1 = *(const short8*)&Ks[buf][(c * 16 + l15) * KST + (t + 1) * 32 + quad * 8];
                sB[c] = __builtin_amdgcn_mfma_f32_16x16x32_bf16(qf[t + 1], b1, sB[c], 0, 0, 0);
            }
        }
        // --- P = exp(S); accumulate denom with the bf16-rounded value ---
        #pragma unroll
        for (int c = 0; c < 2; c++) {
            #pragma unroll
            for (int r = 0; r < 4; r++) {
                const float p = __expf(fminf(sA[c][r] + sB[c][r], 30.0f));
                const unsigned short pb = f_to_bf16bits(p);
                dsum[r] += bf16bits_to_f(pb);
                Ps[(16 * wave + quad * 4 + r) * PST + c * 16 + l15] = pb;
            }
        }
        barrier_lgkm0();   // B2: P visible; K(it+1) DMA stays outstanding

        // --- O[0:64][128w:128w+128] += P @ V (A from LDS, B from regs) ---
        short8 ap[4];
        #pragma unroll
        for (int i = 0; i < 4; i++) ap[i] = *(const short8*)&Ps[(16 * i + l15) * PST + quad * 8];
        #pragma unroll
        for (int c = 0; c < 8; c++) {
            #pragma unroll
            for (int i = 0; i < 4; i++)
                oacc[i][c] = __builtin_amdgcn_mfma_f32_16x16x32_bf16(ap[i], vf[c], oacc[i][c], 0, 0, 0);
        }
        // no 3rd barrier: next B1 orders PV Ps-reads vs next P-writes
    }

    // row-sum the per-lane denominator partials
    #pragma unroll
    for (int r = 0; r < 4; r++) {
        float v = dsum[r];
        v += __shfl_xor(v, 1);
        v += __shfl_xor(v, 2);
        v += __shfl_xor(v, 4);
        v += __shfl_xor(v, 8);
        dsum[r] = v;
    }
    if (l15 == 0) {
        #pragma unroll
        for (int r = 0; r < 4; r++)
            denom[(size_t)sp * 8192 + rowbase + 16 * wave + quad * 4 + r] = dsum[r];
    }

    // store bf16 numerator partials, permuted: [row][wave][l15][c] -> b128
    #pragma unroll
    for (int i = 0; i < 4; i++) {
        #pragma unroll
        for (int r = 0; r < 4; r++) {
            const size_t row = rowbase + 16 * i + quad * 4 + r;
            short8 pk;
            #pragma unroll
            for (int c = 0; c < 8; c++) pk[c] = (short)f_to_bf16bits(oacc[i][c][r]);
            *(short8*)&num[((size_t)sp * 8192 + row) * 512 + wave * 128 + l15 * 8] = pk;
        }
    }
}

// =====================================================================
// Combine: out = (sum_sp num) / (sum_sp denom), fp32 out.
// thread = (srow, w, l15); reads permuted num as b128, writes 8 dwords
// at d = w*128 + 16c + l15.
// =====================================================================
__global__ __launch_bounds__(256) void combine_kernel(
    const unsigned short* __restrict__ num,
    const float* __restrict__ denom,
    float* __restrict__ out,
    int nsplit)
{
    const int gid = blockIdx.x * 256 + threadIdx.x;
    const int srow = gid >> 6;            // 0..8191
    const int sub = gid & 63;
    const int w = sub >> 4, l15 = sub & 15;
    float s[8];
    #pragma unroll
    for (int e = 0; e < 8; e++) s[e] = 0.f;
    float den = 0.f;
    for (int sp = 0; sp < nsplit; sp++) {
        den += denom[(size_t)sp * 8192 + srow];
        short8 v = *(const short8*)(num + ((size_t)sp * 8192 + srow) * 512 + w * 128 + l15 * 8);
        #pragma unroll
        for (int e = 0; e < 8; e++) s[e] += bf16bits_to_f((unsigned short)v[e]);
    }
    const float inv = 1.0f / den;
    float* op = out + (size_t)srow * 512 + w * 128 + l15;
    #pragma unroll
    for (int c = 0; c < 8; c++) op[16 * c] = s[c] * inv;
}

// =====================================================================
extern "C" void kernel_launch(void* const* d_in, const int* in_sizes, int n_in,
                              void* d_out, int out_size, void* d_ws, size_t ws_size,
                              hipStream_t stream)
{
    (void)in_sizes; (void)n_in; (void)out_size;
    const float* Qin = (const float*)d_in[0];
    const float* Kin = (const float*)d_in[1];
    const float* Vin = (const float*)d_in[2];
    const float* Wq  = (const float*)d_in[3];
    const float* bq  = (const float*)d_in[4];
    const float* Wk  = (const float*)d_in[5];
    const float* bk  = (const float*)d_in[6];
    const float* Wv  = (const float*)d_in[7];
    const float* bv  = (const float*)d_in[8];

    const size_t M   = (size_t)8192 * 512;   // 4,194,304 elems
    const size_t WS_ = (size_t)512 * 512;

    // ws layout (bf16 elems): [slotA: conv inputs / num partials][qs][ks][vT][Wc x3][bc x3][denom f32]
    auto need = [&](size_t sa, int ns) -> size_t {
        return (sa + 3 * M) * 2 + 3 * WS_ * 2 + 3 * 512 * 2 + 64 + (size_t)ns * 8192 * 4;
    };
    int nsplit; size_t sa; bool batched;
    if      (ws_size >= need(4 * M, 4)) { nsplit = 4; sa = 4 * M; batched = true; }
    else if (ws_size >= need(3 * M, 2)) { nsplit = 2; sa = 3 * M; batched = true; }
    else                                { nsplit = 1; sa = 1 * M; batched = false; }

    unsigned short* ws    = (unsigned short*)d_ws;
    unsigned short* slotA = ws;                 // conv inputs, later numb
    unsigned short* qs    = ws + sa;
    unsigned short* ks    = qs + M;
    unsigned short* vT    = ks + M;
    unsigned short* Wc    = vT + M;             // 3 slots stride WS_
    unsigned short* bc    = Wc + 3 * WS_;       // 3 slots stride 512
    float* denom = (float*)(((uintptr_t)(bc + 3 * 512) + 15) & ~(uintptr_t)15);
    unsigned short* numb = slotA;

    const float qscale = 1.0f / sqrtf(512.0f);

    if (batched) {
        conv_all_kernel<<<dim3(13059), dim3(256), 0, stream>>>(
            Qin, Kin, Vin, Wq, Wk, Wv, bq, bk, bv, slotA, Wc, bc);
        proj_kernel<<<dim3(256, 3), dim3(256), 0, stream>>>(
            slotA, M, 0, Wc, bc, qs, ks, vT, qscale);
    } else {
        conv_wb_kernel<<<dim3(257, 3), dim3(256), 0, stream>>>(Wq, Wk, Wv, bq, bk, bv, Wc, bc);
        const float* Xin[3] = { Qin, Kin, Vin };
        for (int m = 0; m < 3; m++) {
            conv1_kernel<<<dim3(4096), dim3(256), 0, stream>>>(Xin[m], slotA);
            proj_kernel<<<dim3(256, 1), dim3(256), 0, stream>>>(
                slotA, 0, m, Wc, bc, qs, ks, vT, qscale);
        }
    }

    if (nsplit == 4)
        attn_kernel<4><<<dim3(512), dim3(256), 0, stream>>>(qs, ks, vT, numb, denom);
    else if (nsplit == 2)
        attn_kernel<2><<<dim3(256), dim3(256), 0, stream>>>(qs, ks, vT, numb, denom);
    else
        attn_kernel<1><<<dim3(128), dim3(256), 0, stream>>>(qs, ks, vT, numb, denom);

    combine_kernel<<<dim3(2048), dim3(256), 0, stream>>>(
        numb, denom, (float*)d_out, nsplit);
}